// Round 1
// baseline (697.199 us; speedup 1.0000x reference)
//
#include <hip/hip_runtime.h>
#include <hip/hip_fp16.h>

typedef _Float16 h2v __attribute__((ext_vector_type(2)));
typedef _Float16 f16x8 __attribute__((ext_vector_type(8)));
typedef float f32x4 __attribute__((ext_vector_type(4)));
typedef unsigned int u32;
typedef unsigned short u16;

#define NB 256
#define NP 512
#define NH 256
#define NCOL 768

// ws layout in dwords (all fp16-pair packed weights)
// Wh region: MFMA B-fragments. dword F = (((w*48 + f)*64 + l)*4 + d)
//   f = t*8 + kt (t = N-tile 0..5, kt = K-tile 0..7)
//   halves (2d, 2d+1) = Wh[k][col], Wh[k+1][col]
//   k = kt*32 + (l>>4)*8 + 2d, col = w*96 + t*16 + (l&15)
#define OFF_WH 0
#define LEN_WH 98304            // 8 waves * 48 frags * 64 lanes * 4 dwords
#define OFF_WI (OFF_WH + LEN_WH)      // 98304
#define LEN_WI 6912             // 9 k-pairs * 768 cols
#define OFF_W1 (OFF_WI + LEN_WI)      // 105216
#define LEN_W1 68096            // 2 * 133 * 256
#define OFF_W2 (OFF_W1 + LEN_W1)      // 173312
#define LEN_W2 65536            // 2 * 128 * 256
#define OFF_W3 (OFF_W2 + LEN_W2)      // 238848
#define LEN_W3 256              // 2 * 128
#define WS_DWORDS (OFF_W3 + LEN_W3)   // 239104 dwords = 956416 B

__device__ __forceinline__ u32 pack2(float lo, float hi) {
    h2v v; v.x = (_Float16)lo; v.y = (_Float16)hi;
    return __builtin_bit_cast(u32, v);
}

__device__ __forceinline__ float fdot2(u32 a, u32 b, float c) {
#if __has_builtin(__builtin_amdgcn_fdot2)
    return __builtin_amdgcn_fdot2(__builtin_bit_cast(h2v, a),
                                  __builtin_bit_cast(h2v, b), c, false);
#else
    h2v x = __builtin_bit_cast(h2v, a), y = __builtin_bit_cast(h2v, b);
    return c + (float)x.x * (float)y.x + (float)x.y * (float)y.y;
#endif
}

// ---------------- pack kernel: fp32 weights -> fp16-pair layouts in ws ----
__global__ __launch_bounds__(256) void pack_kernel(
    const float* __restrict__ Wi, const float* __restrict__ Whrz,
    const float* __restrict__ Whn, const float* __restrict__ W1,
    const float* __restrict__ W2, const float* __restrict__ W3,
    u32* __restrict__ ws)
{
    for (int F = blockIdx.x * 256 + threadIdx.x; F < WS_DWORDS; F += gridDim.x * 256) {
        u32 val;
        if (F < OFF_WI) {
            // MFMA B-fragment pack (see layout comment above)
            int d = F & 3; int r = F >> 2;
            int l = r & 63; int q = r >> 6;      // q = w*48 + f
            int f = q % 48; int w = q / 48;
            int t = f >> 3; int kt = f & 7;
            int k = kt * 32 + ((l >> 4) << 3) + 2 * d;
            int col = w * 96 + t * 16 + (l & 15);
            float lo, hi;
            if (col < 512) { lo = Whrz[k * 512 + col]; hi = Whrz[(k + 1) * 512 + col]; }
            else { lo = Whn[k * 256 + (col - 512)]; hi = Whn[(k + 1) * 256 + (col - 512)]; }
            val = pack2(lo, hi);
        } else if (F < OFF_W1) {
            int j = F - OFF_WI; int kk = j / NCOL; int col = j % NCOL;
            int k = 2 * kk;
            float lo = Wi[k * NCOL + col];
            float hi = (k + 1 < 17) ? Wi[(k + 1) * NCOL + col] : 0.f;
            val = pack2(lo, hi);
        } else if (F < OFF_W2) {
            int j = F - OFF_W1; int c = j / (133 * 256); int r = j % (133 * 256);
            int kk = r >> 8; int o = r & 255;
            int k = 2 * kk;
            float lo = W1[(c * 265 + k) * 256 + o];
            float hi = (k + 1 < 265) ? W1[(c * 265 + k + 1) * 256 + o] : 0.f;
            val = pack2(lo, hi);
        } else if (F < OFF_W3) {
            int j = F - OFF_W2; int c = j >> 15; int r = j & 32767;
            int kk = r >> 8; int o = r & 255;
            float lo = W2[(c * 256 + 2 * kk) * 256 + o];
            float hi = W2[(c * 256 + 2 * kk + 1) * 256 + o];
            val = pack2(lo, hi);
        } else {
            int j = F - OFF_W3; int c = j >> 7; int jj = j & 127;
            float lo = W3[c * 256 + 2 * jj];
            float hi = W3[c * 256 + 2 * jj + 1];
            val = pack2(lo, hi);
        }
        ws[F] = val;
    }
}

// ---------------- main kernel: one batch row per workgroup --------------
// h@Wh runs on the MFMA pipe: A-frag = h broadcast into all 16 rows
// (every row of C is then the same column dot product -> lane&15 = col,
// reg0 holds the full K=256 sum after 8 chained MFMAs). Each wave owns
// 96 columns x full K, so there is NO cross-wave K reduction.
__global__ __launch_bounds__(512, 2) void qnet_kernel(
    const float* __restrict__ particles, const float* __restrict__ pweights,
    const float* __restrict__ actions, const float* __restrict__ timev,
    const float* __restrict__ bi, const float* __restrict__ bn,
    const float* __restrict__ b1, const float* __restrict__ b2,
    const float* __restrict__ b3, const int* __restrict__ nts,
    const u32* __restrict__ ws, float* __restrict__ out)
{
    __shared__ __align__(16) u32 sWi[LEN_WI];        // 27648 B, Wi fp16 pairs [9][768]
    __shared__ __align__(16) u32 sX[NP * 9];         // 18432 B, x fp16 pairs per step
    __shared__ __align__(16) float sCols[NCOL];      // 3072 B, full-K column sums
    __shared__ __align__(16) u32 sH2[NH / 2];        // 512 B, h as fp16 pairs
    __shared__ __align__(16) float sHf[NH];          // 1024 B, final enc (fp32)
    __shared__ __align__(16) float sMisc[16];        // actions + norm_time

    // MLP-phase overlays (scan arrays dead by then; barriers separate uses)
    u32* sHid = sWi;            // 133 dwords: hidden fp16 pairs
    u16* sL1 = (u16*)sX;        // 512 halves
    u16* sL2 = (u16*)sCols;     // 512 halves

    const int b = blockIdx.x;
    const int tid = threadIdx.x;
    const int lane = tid & 63;
    const int wid = tid >> 6;   // 0..7, owns cols [wid*96, wid*96+96)

    // ---- load this wave's Wh B-fragments (48 frags x 16B per lane) ----
    f16x8 bf[48];
    {
        const uint4* gp = (const uint4*)(ws + OFF_WH) + (wid * 48) * 64 + lane;
        #pragma unroll
        for (int i = 0; i < 48; ++i) bf[i] = __builtin_bit_cast(f16x8, gp[i * 64]);
    }
    // ---- stage Wi pairs into LDS ----
    for (int j = tid; j < LEN_WI; j += 512) sWi[j] = ws[OFF_WI + j];
    // ---- stage this row's x sequence as fp16 pairs ----
    {
        const float4* pr = (const float4*)(particles + (long)b * NP * 16);
        for (int j = tid; j < NP * 4; j += 512) {
            float4 v = pr[j];
            int p = j >> 2, d4 = j & 3;
            sX[p * 9 + d4 * 2]     = pack2(v.x, v.y);
            sX[p * 9 + d4 * 2 + 1] = pack2(v.z, v.w);
        }
        const float* wr = pweights + (long)b * NP;
        for (int p = tid; p < NP; p += 512) sX[p * 9 + 8] = pack2(wr[p], 0.f);
    }
    if (tid < NH / 2) sH2[tid] = 0u;
    if (tid < 8) sMisc[tid] = actions[b * 8 + tid];
    if (tid == 8) sMisc[8] = timev[b] / (float)nts[0];

    float hreg = 0.f, bir = 0.f, biz = 0.f, binn = 0.f, bnn = 0.f;
    if (tid < NH) {
        bir = bi[tid]; biz = bi[NH + tid]; binn = bi[2 * NH + tid]; bnn = bn[tid];
    }
    __syncthreads();

    // A-frag source: 16-lane group g reads halves [kt*32 + g*8, +8) of h,
    // i.e. uint4 index kt*4 + g. Same k-indexing as the packed B-frags, so
    // the K dot product is exact under any (mirrored) HW fragment k-map.
    const uint4* h4 = ((const uint4*)sH2) + (lane >> 4);
    float* colp = sCols + wid * 96 + (lane & 15);

    #pragma unroll 1
    for (int p = 0; p < NP; ++p) {
        // ---- h@Wh on the matrix pipe: 6 N-tiles x 8 chained K-tiles ----
        f32x4 a0 = {0.f, 0.f, 0.f, 0.f}, a1 = a0, a2 = a0, a3 = a0, a4 = a0, a5 = a0;
        #pragma unroll
        for (int kt = 0; kt < 8; ++kt) {
            f16x8 av = __builtin_bit_cast(f16x8, h4[kt * 4]);
            a0 = __builtin_amdgcn_mfma_f32_16x16x32_f16(av, bf[kt],      a0, 0, 0, 0);
            a1 = __builtin_amdgcn_mfma_f32_16x16x32_f16(av, bf[8 + kt],  a1, 0, 0, 0);
            a2 = __builtin_amdgcn_mfma_f32_16x16x32_f16(av, bf[16 + kt], a2, 0, 0, 0);
            a3 = __builtin_amdgcn_mfma_f32_16x16x32_f16(av, bf[24 + kt], a3, 0, 0, 0);
            a4 = __builtin_amdgcn_mfma_f32_16x16x32_f16(av, bf[32 + kt], a4, 0, 0, 0);
            a5 = __builtin_amdgcn_mfma_f32_16x16x32_f16(av, bf[40 + kt], a5, 0, 0, 0);
        }

        // ---- x@Wi part (independent of h): VALU pipe, overlaps MFMA ----
        float xr = 0.f, xz = 0.f, xn = 0.f;
        if (tid < NH) {
            xr = bir; xz = biz; xn = binn;
            const u32* xp = &sX[p * 9];
            #pragma unroll
            for (int kk = 0; kk < 9; ++kk) {
                u32 xv = xp[kk];
                xr = fdot2(sWi[kk * NCOL + tid], xv, xr);
                xz = fdot2(sWi[kk * NCOL + NH + tid], xv, xz);
                xn = fdot2(sWi[kk * NCOL + 2 * NH + tid], xv, xn);
            }
        }

        // every row of C is identical -> lanes 0..15 carry the 16 cols of each tile
        if (lane < 16) {
            colp[0]  = a0[0]; colp[16] = a1[0]; colp[32] = a2[0];
            colp[48] = a3[0]; colp[64] = a4[0]; colp[80] = a5[0];
        }
        __syncthreads();
        // ---- gates (full-K sums: single read per gate) ----
        if (tid < NH) {
            float sr = sCols[tid];
            float sz = sCols[NH + tid];
            float sn = sCols[2 * NH + tid];
            float r = 1.f / (1.f + __expf(-(sr + xr)));
            float z = 1.f / (1.f + __expf(-(sz + xz)));
            float targ = xn + r * (sn + bnn);
            float e2 = __expf(2.f * targ);
            float n = 1.f - 2.f / (e2 + 1.f);   // tanh, saturates correctly at +-inf
            hreg = (1.f - z) * n + z * hreg;
            _Float16 hh = (_Float16)hreg;
            ((u16*)sH2)[tid] = __builtin_bit_cast(u16, hh);
        }
        __syncthreads();
    }

    // ---------------- MLP tail ----------------
    if (tid < NH) sHf[tid] = hreg;
    __syncthreads();
    if (tid < 128) sHid[tid] = pack2(sHf[2 * tid], sHf[2 * tid + 1]);
    else if (tid < 132) { int i = tid - 128; sHid[tid] = pack2(sMisc[2 * i], sMisc[2 * i + 1]); }
    else if (tid == 132) sHid[132] = pack2(sMisc[8], 0.f);
    __syncthreads();
    // L1: 512 outputs (2 critics x 256)
    {
        int c = tid >> 8, o = tid & 255;
        float acc = b1[c * 256 + o];
        const u32* wp = ws + OFF_W1 + c * 133 * 256 + o;
        #pragma unroll 4
        for (int kk = 0; kk < 133; ++kk) acc = fdot2(wp[kk * 256], sHid[kk], acc);
        acc = fmaxf(acc, 0.f);
        _Float16 a16 = (_Float16)acc;
        sL1[tid] = __builtin_bit_cast(u16, a16);
    }
    __syncthreads();
    // L2
    {
        int c = tid >> 8, o = tid & 255;
        float acc = b2[c * 256 + o];
        const u32* wp = ws + OFF_W2 + c * 128 * 256 + o;
        const u32* hp = (const u32*)sL1 + c * 128;
        #pragma unroll 4
        for (int kk = 0; kk < 128; ++kk) acc = fdot2(wp[kk * 256], hp[kk], acc);
        acc = fmaxf(acc, 0.f);
        _Float16 a16 = (_Float16)acc;
        sL2[tid] = __builtin_bit_cast(u16, a16);
    }
    __syncthreads();
    // L3: 2 outputs via wave reduction
    if (tid < 128) {
        int c = tid >> 6, l = tid & 63;
        const u32* wp = ws + OFF_W3 + c * 128;
        const u32* hp = (const u32*)sL2 + c * 128;
        float acc = fdot2(wp[l], hp[l], 0.f);
        acc = fdot2(wp[64 + l], hp[64 + l], acc);
        #pragma unroll
        for (int off = 32; off > 0; off >>= 1) acc += __shfl_down(acc, off);
        if (l == 0) out[b * 2 + c] = acc + b3[c];
    }
}

extern "C" void kernel_launch(void* const* d_in, const int* in_sizes, int n_in,
                              void* d_out, int out_size, void* d_ws, size_t ws_size,
                              hipStream_t stream) {
    const float* particles = (const float*)d_in[0];
    const float* pweights  = (const float*)d_in[1];
    const float* actions   = (const float*)d_in[2];
    const float* timev     = (const float*)d_in[3];
    const float* Wi        = (const float*)d_in[4];
    const float* bi        = (const float*)d_in[5];
    const float* Whrz      = (const float*)d_in[6];
    const float* Whn       = (const float*)d_in[7];
    const float* bn        = (const float*)d_in[8];
    const float* W1        = (const float*)d_in[9];
    const float* b1        = (const float*)d_in[10];
    const float* W2        = (const float*)d_in[11];
    const float* b2        = (const float*)d_in[12];
    const float* W3        = (const float*)d_in[13];
    const float* b3        = (const float*)d_in[14];
    const int*   nts       = (const int*)d_in[15];
    u32* ws = (u32*)d_ws;
    float* outp = (float*)d_out;

    pack_kernel<<<WS_DWORDS / 256, 256, 0, stream>>>(Wi, Whrz, Whn, W1, W2, W3, ws);
    qnet_kernel<<<NB, 512, 0, stream>>>(particles, pweights, actions, timev,
                                        bi, bn, b1, b2, b3, nts, ws, outp);
}

// Round 2
// 629.639 us; speedup vs baseline: 1.1073x; 1.1073x over previous
//
#include <hip/hip_runtime.h>
#include <hip/hip_fp16.h>

typedef _Float16 h2v __attribute__((ext_vector_type(2)));
typedef _Float16 f16x8 __attribute__((ext_vector_type(8)));
typedef float f32x4 __attribute__((ext_vector_type(4)));
typedef unsigned int u32;
typedef unsigned short u16;

#define NB 256
#define NP 512
#define NH 256

// ws layout in dwords
// WH: Wh B-frags. dword F = (((w*48 + f)*64 + l)*4 + d)
//   f = t*8 + kt; t = g*2 + c (g=gate 0..2, c=col-half 0..1), kt = K-tile 0..7
//   k = kt*32 + (l>>4)*8 + 2d (+1 for hi half), col = g*256 + w*32 + c*16 + (l&15)
#define OFF_WH 0
#define LEN_WH 98304            // 8 waves * 48 frags * 64 lanes * 4 dwords
// WIB: Wi B-frags (K=32, single K-tile, rows >=17 zero-padded)
//   dword F-OFF = ((w*6 + t)*64 + l)*4 + d ; k = (l>>4)*8 + 2d ; col as above
#define OFF_WIB (OFF_WH + LEN_WH)      // 98304
#define LEN_WIB 12288           // 8 * 6 * 64 * 4
#define OFF_W1 (OFF_WIB + LEN_WIB)     // 110592
#define LEN_W1 68096            // 2 * 133 * 256
#define OFF_W2 (OFF_W1 + LEN_W1)       // 178688
#define LEN_W2 65536            // 2 * 128 * 256
#define OFF_W3 (OFF_W2 + LEN_W2)       // 244224
#define LEN_W3 256              // 2 * 128
#define WS_DWORDS (OFF_W3 + LEN_W3)    // 244480 dwords = 977920 B

__device__ __forceinline__ u32 pack2(float lo, float hi) {
    h2v v; v.x = (_Float16)lo; v.y = (_Float16)hi;
    return __builtin_bit_cast(u32, v);
}

__device__ __forceinline__ float fdot2(u32 a, u32 b, float c) {
#if __has_builtin(__builtin_amdgcn_fdot2)
    return __builtin_amdgcn_fdot2(__builtin_bit_cast(h2v, a),
                                  __builtin_bit_cast(h2v, b), c, false);
#else
    h2v x = __builtin_bit_cast(h2v, a), y = __builtin_bit_cast(h2v, b);
    return c + (float)x.x * (float)y.x + (float)x.y * (float)y.y;
#endif
}

// ---------------- pack kernel ----------------
__global__ __launch_bounds__(256) void pack_kernel(
    const float* __restrict__ Wi, const float* __restrict__ Whrz,
    const float* __restrict__ Whn, const float* __restrict__ W1,
    const float* __restrict__ W2, const float* __restrict__ W3,
    u32* __restrict__ ws)
{
    for (int F = blockIdx.x * 256 + threadIdx.x; F < WS_DWORDS; F += gridDim.x * 256) {
        u32 val;
        if (F < OFF_WIB) {
            int d = F & 3; int r = F >> 2;
            int l = r & 63; int q = r >> 6;      // q = w*48 + f
            int f = q % 48; int w = q / 48;
            int t = f >> 3; int kt = f & 7;
            int g = t >> 1, c = t & 1;
            int k = kt * 32 + ((l >> 4) << 3) + 2 * d;
            int col = g * 256 + w * 32 + c * 16 + (l & 15);
            float lo, hi;
            if (col < 512) { lo = Whrz[k * 512 + col]; hi = Whrz[(k + 1) * 512 + col]; }
            else { lo = Whn[k * 256 + (col - 512)]; hi = Whn[(k + 1) * 256 + (col - 512)]; }
            val = pack2(lo, hi);
        } else if (F < OFF_W1) {
            int j = F - OFF_WIB;
            int d = j & 3; int r = j >> 2;
            int l = r & 63; int q = r >> 6;      // q = w*6 + t
            int t = q % 6; int w = q / 6;
            int g = t >> 1, c = t & 1;
            int k = ((l >> 4) << 3) + 2 * d;
            int col = g * 256 + w * 32 + c * 16 + (l & 15);
            float lo = (k < 17) ? Wi[k * 768 + col] : 0.f;
            float hi = (k + 1 < 17) ? Wi[(k + 1) * 768 + col] : 0.f;
            val = pack2(lo, hi);
        } else if (F < OFF_W2) {
            int j = F - OFF_W1; int c = j / (133 * 256); int r = j % (133 * 256);
            int kk = r >> 8; int o = r & 255;
            int k = 2 * kk;
            float lo = W1[(c * 265 + k) * 256 + o];
            float hi = (k + 1 < 265) ? W1[(c * 265 + k + 1) * 256 + o] : 0.f;
            val = pack2(lo, hi);
        } else if (F < OFF_W3) {
            int j = F - OFF_W2; int c = j >> 15; int r = j & 32767;
            int kk = r >> 8; int o = r & 255;
            float lo = W2[(c * 256 + 2 * kk) * 256 + o];
            float hi = W2[(c * 256 + 2 * kk + 1) * 256 + o];
            val = pack2(lo, hi);
        } else {
            int j = F - OFF_W3; int c = j >> 7; int jj = j & 127;
            float lo = W3[c * 256 + 2 * jj];
            float hi = W3[c * 256 + 2 * jj + 1];
            val = pack2(lo, hi);
        }
        ws[F] = val;
    }
}

// ---------------- main kernel: one batch row per workgroup --------------
// Wave w owns h-indices [w*32, w*32+32): its 6 MFMA accumulators are the
// r/z/n column sums (full K=256) for exactly those indices, so the GRU
// gates are computed fully in-register. x@Wi is precomputed 16 steps at a
// time via a real (rows=steps) MFMA into sG. One barrier per step,
// double-buffered h.
__global__ __launch_bounds__(512, 2) void qnet_kernel(
    const float* __restrict__ particles, const float* __restrict__ pweights,
    const float* __restrict__ actions, const float* __restrict__ timev,
    const float* __restrict__ bi, const float* __restrict__ bn,
    const float* __restrict__ b1, const float* __restrict__ b2,
    const float* __restrict__ b3, const int* __restrict__ nts,
    const u32* __restrict__ ws, float* __restrict__ out)
{
    __shared__ __align__(16) u32 sX[NP * 16];      // 32768 B, x rows padded to K=32 halves
    __shared__ __align__(16) float sG[8 * 1536];   // 49152 B, x@Wi chunk (16 steps)
    __shared__ __align__(16) u32 sH2[2][128];      // 1024 B, h fp16 pairs, double-buffered
    __shared__ __align__(16) float sHf[NH];        // 1024 B
    __shared__ __align__(16) float sMisc[16];      // 64 B

    const int b = blockIdx.x;
    const int tid = threadIdx.x;
    const int lane = tid & 63;
    const int wid = tid >> 6;   // 0..7

    // ---- Wh B-frags into registers (48 frags x 16B per lane) ----
    f16x8 bfh[48];
    {
        const uint4* gp = (const uint4*)(ws + OFF_WH) + (wid * 48) * 64 + lane;
        #pragma unroll
        for (int i = 0; i < 48; ++i) bfh[i] = __builtin_bit_cast(f16x8, gp[i * 64]);
    }
    // ---- stage x rows as fp16 pairs, padded to 16 pairs (K=32 halves) ----
    {
        const float2* pr2 = (const float2*)(particles + (long)b * NP * 16);
        for (int j = tid; j < NP * 8; j += 512) {
            int p = j >> 3, q = j & 7;
            float2 v = pr2[j];
            sX[p * 16 + q] = pack2(v.x, v.y);
        }
        const float* wr = pweights + (long)b * NP;
        for (int j = tid; j < NP * 8; j += 512) {
            int p = j >> 3, q = j & 7;
            sX[p * 16 + 8 + q] = (q == 0) ? pack2(wr[p], 0.f) : 0u;
        }
    }
    if (tid < 256) ((u32*)sH2)[tid] = 0u;
    if (tid < 8) sMisc[tid] = actions[b * 8 + tid];
    if (tid == 8) sMisc[8] = timev[b] / (float)nts[0];

    // ---- per-lane gate biases (lane l<32 owns h-index j = wid*32+l) ----
    float birL = 0.f, bizL = 0.f, binnL = 0.f, bnnL = 0.f, hreg = 0.f;
    if (lane < 32) {
        int j = wid * 32 + lane;
        birL = bi[j]; bizL = bi[NH + j]; binnL = bi[2 * NH + j]; bnnL = bn[j];
    }
    __syncthreads();

    const uint4* wibp = (const uint4*)(ws + OFF_WIB) + (wid * 6) * 64 + lane;

    #pragma unroll 1
    for (int p = 0; p < NP; ++p) {
        if ((p & 15) == 0) {
            // ---- x@Wi for steps p..p+15: rows = steps, one K-tile ----
            f16x8 av = __builtin_bit_cast(f16x8,
                ((const uint4*)sX)[(p + (lane & 15)) * 4 + (lane >> 4)]);
            f32x4 z4 = {0.f, 0.f, 0.f, 0.f};
            f32x4 g0 = __builtin_amdgcn_mfma_f32_16x16x32_f16(av, __builtin_bit_cast(f16x8, wibp[0 * 64]), z4, 0, 0, 0);
            f32x4 g1 = __builtin_amdgcn_mfma_f32_16x16x32_f16(av, __builtin_bit_cast(f16x8, wibp[1 * 64]), z4, 0, 0, 0);
            f32x4 g2 = __builtin_amdgcn_mfma_f32_16x16x32_f16(av, __builtin_bit_cast(f16x8, wibp[2 * 64]), z4, 0, 0, 0);
            f32x4 g3 = __builtin_amdgcn_mfma_f32_16x16x32_f16(av, __builtin_bit_cast(f16x8, wibp[3 * 64]), z4, 0, 0, 0);
            f32x4 g4 = __builtin_amdgcn_mfma_f32_16x16x32_f16(av, __builtin_bit_cast(f16x8, wibp[4 * 64]), z4, 0, 0, 0);
            f32x4 g5 = __builtin_amdgcn_mfma_f32_16x16x32_f16(av, __builtin_bit_cast(f16x8, wibp[5 * 64]), z4, 0, 0, 0);
            // C layout: step = (lane>>4)*4 + reg, col16 = lane&15
            int sb = (lane >> 4) << 2;
            float* gw = sG + wid * 1536 + (lane & 15);
            #pragma unroll
            for (int r = 0; r < 4; ++r) {
                gw[(sb + r) * 32]          = g0[r];
                gw[(sb + r) * 32 + 16]     = g1[r];
                gw[512 + (sb + r) * 32]    = g2[r];
                gw[512 + (sb + r) * 32 + 16] = g3[r];
                gw[1024 + (sb + r) * 32]   = g4[r];
                gw[1024 + (sb + r) * 32 + 16] = g5[r];
            }
            __syncthreads();
        }

        // ---- prefetch this step's x@Wi sums (independent of h) ----
        float gR = 0.f, gZ = 0.f, gN = 0.f;
        {
            const float* gp = sG + wid * 1536 + (p & 15) * 32 + (lane & 31);
            gR = gp[0]; gZ = gp[512]; gN = gp[1024];
        }

        // ---- h@Wh on the matrix pipe: 6 gate-tiles x 8 chained K-tiles ----
        const u32* hbuf = sH2[p & 1];
        f32x4 a0 = {0.f, 0.f, 0.f, 0.f}, a1 = a0, a2 = a0, a3 = a0, a4 = a0, a5 = a0;
        #pragma unroll
        for (int kt = 0; kt < 8; ++kt) {
            f16x8 hv = __builtin_bit_cast(f16x8, ((const uint4*)hbuf)[kt * 4 + (lane >> 4)]);
            a0 = __builtin_amdgcn_mfma_f32_16x16x32_f16(hv, bfh[kt],      a0, 0, 0, 0);
            a1 = __builtin_amdgcn_mfma_f32_16x16x32_f16(hv, bfh[8 + kt],  a1, 0, 0, 0);
            a2 = __builtin_amdgcn_mfma_f32_16x16x32_f16(hv, bfh[16 + kt], a2, 0, 0, 0);
            a3 = __builtin_amdgcn_mfma_f32_16x16x32_f16(hv, bfh[24 + kt], a3, 0, 0, 0);
            a4 = __builtin_amdgcn_mfma_f32_16x16x32_f16(hv, bfh[32 + kt], a4, 0, 0, 0);
            a5 = __builtin_amdgcn_mfma_f32_16x16x32_f16(hv, bfh[40 + kt], a5, 0, 0, 0);
        }

        // ---- gates fully in-register (lane l<32 owns h[wid*32+l]) ----
        bool hic = (lane & 16) != 0;
        float srm = hic ? a1[0] : a0[0];
        float szm = hic ? a3[0] : a2[0];
        float snm = hic ? a5[0] : a4[0];
        if (lane < 32) {
            float xr = gR + birL + srm;
            float xz = gZ + bizL + szm;
            float xn = gN + binnL;
            float r = 1.f / (1.f + __expf(-xr));
            float z = 1.f / (1.f + __expf(-xz));
            float targ = xn + r * (snm + bnnL);
            float e2 = __expf(2.f * targ);
            float n = 1.f - 2.f / (e2 + 1.f);
            hreg = (1.f - z) * n + z * hreg;
            _Float16 hh = (_Float16)hreg;
            ((u16*)sH2[(p + 1) & 1])[wid * 32 + lane] = __builtin_bit_cast(u16, hh);
        }
        __syncthreads();
    }

    // ---------------- MLP tail ----------------
    if (lane < 32) sHf[wid * 32 + lane] = hreg;
    __syncthreads();
    u32* sHid = (u32*)sG;             // 133 dwords
    u16* sL1 = (u16*)(sG + 512);      // 512 halves
    u16* sL2 = (u16*)(sG + 1024);     // 512 halves
    if (tid < 128) sHid[tid] = pack2(sHf[2 * tid], sHf[2 * tid + 1]);
    else if (tid < 132) { int i = tid - 128; sHid[tid] = pack2(sMisc[2 * i], sMisc[2 * i + 1]); }
    else if (tid == 132) sHid[132] = pack2(sMisc[8], 0.f);
    __syncthreads();
    // L1: 512 outputs (2 critics x 256)
    {
        int c = tid >> 8, o = tid & 255;
        float acc = b1[c * 256 + o];
        const u32* wp = ws + OFF_W1 + c * 133 * 256 + o;
        #pragma unroll 4
        for (int kk = 0; kk < 133; ++kk) acc = fdot2(wp[kk * 256], sHid[kk], acc);
        acc = fmaxf(acc, 0.f);
        _Float16 a16 = (_Float16)acc;
        sL1[tid] = __builtin_bit_cast(u16, a16);
    }
    __syncthreads();
    // L2
    {
        int c = tid >> 8, o = tid & 255;
        float acc = b2[c * 256 + o];
        const u32* wp = ws + OFF_W2 + c * 128 * 256 + o;
        const u32* hp = (const u32*)sL1 + c * 128;
        #pragma unroll 4
        for (int kk = 0; kk < 128; ++kk) acc = fdot2(wp[kk * 256], hp[kk], acc);
        acc = fmaxf(acc, 0.f);
        _Float16 a16 = (_Float16)acc;
        sL2[tid] = __builtin_bit_cast(u16, a16);
    }
    __syncthreads();
    // L3: 2 outputs via wave reduction
    if (tid < 128) {
        int c = tid >> 6, l = tid & 63;
        const u32* wp = ws + OFF_W3 + c * 128;
        const u32* hp = (const u32*)sL2 + c * 128;
        float acc = fdot2(wp[l], hp[l], 0.f);
        acc = fdot2(wp[64 + l], hp[64 + l], acc);
        #pragma unroll
        for (int off = 32; off > 0; off >>= 1) acc += __shfl_down(acc, off);
        if (l == 0) out[b * 2 + c] = acc + b3[c];
    }
}

extern "C" void kernel_launch(void* const* d_in, const int* in_sizes, int n_in,
                              void* d_out, int out_size, void* d_ws, size_t ws_size,
                              hipStream_t stream) {
    const float* particles = (const float*)d_in[0];
    const float* pweights  = (const float*)d_in[1];
    const float* actions   = (const float*)d_in[2];
    const float* timev     = (const float*)d_in[3];
    const float* Wi        = (const float*)d_in[4];
    const float* bi        = (const float*)d_in[5];
    const float* Whrz      = (const float*)d_in[6];
    const float* Whn       = (const float*)d_in[7];
    const float* bn        = (const float*)d_in[8];
    const float* W1        = (const float*)d_in[9];
    const float* b1        = (const float*)d_in[10];
    const float* W2        = (const float*)d_in[11];
    const float* b2        = (const float*)d_in[12];
    const float* W3        = (const float*)d_in[13];
    const float* b3        = (const float*)d_in[14];
    const int*   nts       = (const int*)d_in[15];
    u32* ws = (u32*)d_ws;
    float* outp = (float*)d_out;

    pack_kernel<<<(WS_DWORDS + 255) / 256, 256, 0, stream>>>(Wi, Whrz, Whn, W1, W2, W3, ws);
    qnet_kernel<<<NB, 512, 0, stream>>>(particles, pweights, actions, timev,
                                        bi, bn, b1, b2, b3, nts, ws, outp);
}